// Round 6
// baseline (1239.057 us; speedup 1.0000x reference)
//
#include <hip/hip_runtime.h>
#include <math.h>

// Problem constants (match reference)
constexpr int NN = 100000;     // nodes
constexpr int DF = 512;        // input features
constexpr int C1 = 32;         // layer-1 width
constexpr int C2 = 16;         // layer-2 width
constexpr int NE = 3200000;    // edges
#define EPS_NORM 1e-7f

constexpr int SCAN_B = 512;
constexpr int SCAN_NBLK = (NN + SCAN_B - 1) / SCAN_B;   // 196

// ---------------------------------------------------------------------------
// gemm1: XW1[row][0..31] = X[row][:] @ W1   (one thread per row)
// 64-thread blocks -> 1563 blocks, even CU distribution; 8-deep float4
// preload for ILP (6 waves/CU total, need deep loads to cover HBM latency).
// W1 accesses are wave-uniform -> scalar s_load broadcasts.
// ---------------------------------------------------------------------------
__global__ __launch_bounds__(64) void gemm1_k(const float* __restrict__ X,
                                              const float* __restrict__ W1,
                                              float* __restrict__ XW1) {
    int row = blockIdx.x * 64 + threadIdx.x;
    if (row >= NN) return;
    float acc[C1];
#pragma unroll
    for (int j = 0; j < C1; ++j) acc[j] = 0.f;
    const float4* xr = reinterpret_cast<const float4*>(X + (size_t)row * DF);
#pragma unroll 1
    for (int k4 = 0; k4 < DF / 4; k4 += 8) {
        float4 xv[8];
#pragma unroll
        for (int u = 0; u < 8; ++u) xv[u] = xr[k4 + u];
#pragma unroll
        for (int u = 0; u < 8; ++u) {
            const float* w = W1 + (size_t)(k4 + u) * 4 * C1;   // uniform
#pragma unroll
            for (int j = 0; j < C1; ++j) acc[j] = fmaf(xv[u].x, w[j], acc[j]);
#pragma unroll
            for (int j = 0; j < C1; ++j) acc[j] = fmaf(xv[u].y, w[C1 + j], acc[j]);
#pragma unroll
            for (int j = 0; j < C1; ++j) acc[j] = fmaf(xv[u].z, w[2 * C1 + j], acc[j]);
#pragma unroll
            for (int j = 0; j < C1; ++j) acc[j] = fmaf(xv[u].w, w[3 * C1 + j], acc[j]);
        }
    }
    float4* o = reinterpret_cast<float4*>(XW1 + (size_t)row * C1);
#pragma unroll
    for (int q = 0; q < C1 / 4; ++q)
        o[q] = make_float4(acc[4 * q], acc[4 * q + 1], acc[4 * q + 2], acc[4 * q + 3]);
}

// ---------------------------------------------------------------------------
// gemm2: HW2[row][0..15] = relu(H1[row][:]) @ W2   (one thread per row)
// ---------------------------------------------------------------------------
__global__ __launch_bounds__(64) void gemm2_k(const float* __restrict__ H1,
                                              const float* __restrict__ W2,
                                              float* __restrict__ HW2) {
    int row = blockIdx.x * 64 + threadIdx.x;
    if (row >= NN) return;
    float h[C1];
    const float4* hr = reinterpret_cast<const float4*>(H1 + (size_t)row * C1);
#pragma unroll
    for (int q = 0; q < C1 / 4; ++q) {
        float4 v = hr[q];
        h[4 * q + 0] = fmaxf(v.x, 0.f);
        h[4 * q + 1] = fmaxf(v.y, 0.f);
        h[4 * q + 2] = fmaxf(v.z, 0.f);
        h[4 * q + 3] = fmaxf(v.w, 0.f);
    }
    float acc[C2];
#pragma unroll
    for (int j = 0; j < C2; ++j) acc[j] = 0.f;
#pragma unroll
    for (int k = 0; k < C1; ++k) {
        const float* w = W2 + k * C2;   // uniform
#pragma unroll
        for (int j = 0; j < C2; ++j) acc[j] = fmaf(h[k], w[j], acc[j]);
    }
    float4* o = reinterpret_cast<float4*>(HW2 + (size_t)row * C2);
#pragma unroll
    for (int q = 0; q < C2 / 4; ++q)
        o[q] = make_float4(acc[4 * q], acc[4 * q + 1], acc[4 * q + 2], acc[4 * q + 3]);
}

// ---------------------------------------------------------------------------
// CSR build: histogram -> 3-kernel scan -> scatter edge ids into buckets.
// ---------------------------------------------------------------------------
__global__ __launch_bounds__(256) void hist_k(const int* __restrict__ rows,
                                              int* __restrict__ cnt) {
    int stride = gridDim.x * 256;
    for (int e = blockIdx.x * 256 + threadIdx.x; e < NE; e += stride)
        atomicAdd(&cnt[rows[e]], 1);
}

// block-level inclusive scan (Hillis-Steele in LDS); writes block sums
__global__ __launch_bounds__(SCAN_B) void scan1_k(const int* __restrict__ cnt,
                                                  int* __restrict__ rowend,
                                                  int* __restrict__ sums) {
    __shared__ int sh[SCAN_B];
    int t = threadIdx.x;
    int g = blockIdx.x * SCAN_B + t;
    sh[t] = (g < NN) ? cnt[g] : 0;
    __syncthreads();
#pragma unroll
    for (int off = 1; off < SCAN_B; off <<= 1) {
        int u = (t >= off) ? sh[t - off] : 0;
        __syncthreads();
        sh[t] += u;
        __syncthreads();
    }
    if (g < NN) rowend[g] = sh[t];
    if (t == SCAN_B - 1) sums[blockIdx.x] = sh[t];
}

// exclusive scan of the block sums (single block)
__global__ __launch_bounds__(256) void scan2_k(int* __restrict__ sums) {
    __shared__ int sh[256];
    int t = threadIdx.x;
    sh[t] = (t < SCAN_NBLK) ? sums[t] : 0;
    __syncthreads();
#pragma unroll
    for (int off = 1; off < 256; off <<= 1) {
        int u = (t >= off) ? sh[t - off] : 0;
        __syncthreads();
        sh[t] += u;
        __syncthreads();
    }
    if (t < SCAN_NBLK) sums[t] = t ? sh[t - 1] : 0;
}

// add block offsets; derive scatter cursors (= row starts)
__global__ __launch_bounds__(SCAN_B) void scan3_k(const int* __restrict__ cnt,
                                                  int* __restrict__ rowend,
                                                  int* __restrict__ cursor,
                                                  const int* __restrict__ sums) {
    int g = blockIdx.x * SCAN_B + threadIdx.x;
    if (g >= NN) return;
    int e = rowend[g] + sums[blockIdx.x];
    rowend[g] = e;
    cursor[g] = e - cnt[g];
}

__global__ __launch_bounds__(256) void scatter_k(const int* __restrict__ rows,
                                                 int* __restrict__ cursor,
                                                 int* __restrict__ bucket) {
    int stride = gridDim.x * 256;
    for (int e = blockIdx.x * 256 + threadIdx.x; e < NE; e += stride) {
        int pos = atomicAdd(&cursor[rows[e]], 1);
        bucket[pos] = e;
    }
}

// ---------------------------------------------------------------------------
// apply: gather-SpMM, one wave per output row.
// lane j = lane & (F-1) handles feature j; sub-groups of F lanes process
// 64/F edges per iteration. Optional fused ReLU (layer 1) and row-L2
// normalization (layer 2 epilogue).
// ---------------------------------------------------------------------------
template <int F, bool RELU, bool NORM>
__global__ __launch_bounds__(256) void apply_k(const int* __restrict__ bucket,
                                               const int* __restrict__ cols,
                                               const float* __restrict__ vals,
                                               const int* __restrict__ cnt,
                                               const int* __restrict__ rowend,
                                               const float* __restrict__ Hin,
                                               float* __restrict__ Hout) {
    constexpr int EPI = 64 / F;
    int r = (blockIdx.x * 256 + threadIdx.x) >> 6;   // wave id == row
    if (r >= NN) return;
    int lane = threadIdx.x & 63;
    int j = lane & (F - 1);
    int sub = lane >> ((F == 32) ? 5 : 4);
    int end = rowend[r];
    int start = end - cnt[r];
    float acc = 0.f;
    for (int i = start + sub; i < end; i += EPI) {
        int e = bucket[i];
        int c = cols[e];
        float v = vals[e];
        acc = fmaf(v, Hin[(size_t)c * F + j], acc);
    }
    // combine sub-group partials: afterwards every lane holds feature j's total
#pragma unroll
    for (int m = F; m < 64; m <<= 1) acc += __shfl_xor(acc, m);
    if (RELU) acc = fmaxf(acc, 0.f);
    if (NORM) {
        float s = acc * acc;
#pragma unroll
        for (int m = 1; m < F; m <<= 1) s += __shfl_xor(s, m);
        acc = acc / fmaxf(sqrtf(s), EPS_NORM);
    }
    if (lane < F) Hout[(size_t)r * F + j] = acc;
}

// ---------------------------------------------------------------------------
// Fallback path (round-4 scatter-atomic version) if ws_size is too small.
// ---------------------------------------------------------------------------
template <int F>
__global__ __launch_bounds__(256) void spmm_k(const int* __restrict__ rows,
                                              const int* __restrict__ cols,
                                              const float* __restrict__ vals,
                                              const float* __restrict__ Hin,
                                              float* __restrict__ Hout) {
    constexpr int SH = (F == 32) ? 5 : 4;
    constexpr int MSK = F - 1;
    long long total = (long long)NE << SH;
    long long stride = (long long)gridDim.x * 256;
    for (long long idx = (long long)blockIdx.x * 256 + threadIdx.x; idx < total;
         idx += stride) {
        int e = (int)(idx >> SH);
        int j = (int)(idx & MSK);
        float contrib = vals[e] * Hin[(size_t)cols[e] * F + j];
        unsafeAtomicAdd(&Hout[(size_t)rows[e] * F + j], contrib);
    }
}

__global__ __launch_bounds__(256) void norm_k(float* __restrict__ H) {
    int t = blockIdx.x * 256 + threadIdx.x;
    if (t >= NN * C2) return;
    float v = H[t];
    float s = v * v;
#pragma unroll
    for (int m = 1; m < C2; m <<= 1) s += __shfl_xor(s, m, C2);
    H[t] = v / fmaxf(sqrtf(s), EPS_NORM);
}

extern "C" void kernel_launch(void* const* d_in, const int* in_sizes, int n_in,
                              void* d_out, int out_size, void* d_ws, size_t ws_size,
                              hipStream_t stream) {
    const float* X = (const float*)d_in[0];
    const float* W1 = (const float*)d_in[1];
    const float* W2 = (const float*)d_in[2];
    const int* lap_rows = (const int*)d_in[3];
    const int* lap_cols = (const int*)d_in[4];
    const float* vals = (const float*)d_in[5];
    float* out = (float*)d_out;

    // workspace layout
    float* XW1 = (float*)d_ws;                       // NN*C1
    float* H1 = XW1 + (size_t)NN * C1;               // NN*C1
    float* HW2 = H1 + (size_t)NN * C1;               // NN*C2
    int* cnt = (int*)(HW2 + (size_t)NN * C2);        // NN
    int* rowend = cnt + NN;                          // NN
    int* cursor = rowend + NN;                       // NN
    int* sums = cursor + NN;                         // 256
    int* bucket = sums + 256;                        // NE
    size_t need = (size_t)((char*)(bucket + NE) - (char*)d_ws);

    int rowBlocks64 = (NN + 63) / 64;

    if (ws_size >= need) {
        // --- CSR build (graph fixed per call; rebuilt every call) ---
        hipMemsetAsync(cnt, 0, (size_t)NN * sizeof(int), stream);
        hist_k<<<2048, 256, 0, stream>>>(lap_rows, cnt);
        scan1_k<<<SCAN_NBLK, SCAN_B, 0, stream>>>(cnt, rowend, sums);
        scan2_k<<<1, 256, 0, stream>>>(sums);
        scan3_k<<<SCAN_NBLK, SCAN_B, 0, stream>>>(cnt, rowend, cursor, sums);
        scatter_k<<<2048, 256, 0, stream>>>(lap_rows, cursor, bucket);

        // --- pipeline ---
        gemm1_k<<<rowBlocks64, 64, 0, stream>>>(X, W1, XW1);
        apply_k<C1, true, false><<<(NN * 64 + 255) / 256, 256, 0, stream>>>(
            bucket, lap_cols, vals, cnt, rowend, XW1, H1);
        gemm2_k<<<rowBlocks64, 64, 0, stream>>>(H1, W2, HW2);
        apply_k<C2, false, true><<<(NN * 64 + 255) / 256, 256, 0, stream>>>(
            bucket, lap_cols, vals, cnt, rowend, HW2, out);
    } else {
        // fallback: scatter-atomic path (needs only 32 MB of ws)
        hipMemsetAsync(H1, 0, (size_t)NN * C1 * sizeof(float), stream);
        hipMemsetAsync(out, 0, (size_t)NN * C2 * sizeof(float), stream);
        gemm1_k<<<rowBlocks64, 64, 0, stream>>>(X, W1, XW1);
        spmm_k<C1><<<16384, 256, 0, stream>>>(lap_rows, lap_cols, vals, XW1, H1);
        gemm2_k<<<rowBlocks64, 64, 0, stream>>>(H1, W2, HW2);
        spmm_k<C2><<<8192, 256, 0, stream>>>(lap_rows, lap_cols, vals, HW2, out);
        norm_k<<<((NN * C2) + 255) / 256, 256, 0, stream>>>(out);
    }
}